// Round 1
// baseline (626.398 us; speedup 1.0000x reference)
//
#include <hip/hip_runtime.h>

#define B_ 16
#define C_ 64
#define H_ 128
#define W_ 128
#define E_ 4
#define HW_ (H_ * W_)
#define CHUNK 32

// ws layout (floats):
//   [0, 147456)          : wT [4][64ci][9tap][64co]
//   [147456, 148480)     : pooled [16][64]
//   [148480, 148544)     : ew [16][4]
#define WT_OFF 0
#define POOLED_OFF 147456
#define EW_OFF 148480

// ---------------- pool: mean over HW per (b,c) ----------------
__global__ __launch_bounds__(256) void pool_kernel(const float* __restrict__ in,
                                                   float* __restrict__ pooled) {
    const int bc = blockIdx.x;  // 0..1023
    const float* p = in + (size_t)bc * HW_;
    float s = 0.f;
    for (int i = threadIdx.x; i < HW_ / 4; i += 256) {
        float4 v = ((const float4*)p)[i];
        s += v.x + v.y + v.z + v.w;
    }
    // wave64 reduce
    for (int off = 32; off; off >>= 1) s += __shfl_down(s, off);
    __shared__ float red[4];
    const int lane = threadIdx.x & 63, wv = threadIdx.x >> 6;
    if (lane == 0) red[wv] = s;
    __syncthreads();
    if (threadIdx.x == 0) {
        pooled[bc] = (red[0] + red[1] + red[2] + red[3]) * (1.0f / (float)HW_);
    }
}

// ---------------- gate: logits -> softmax -> top-2 dense weights ----------------
__global__ void gate_kernel(const float* __restrict__ pooled,
                            const float* __restrict__ gate_w,
                            const float* __restrict__ gate_b,
                            float* __restrict__ ew) {
    const int b = threadIdx.x;
    if (b >= B_) return;
    float lg[E_];
    for (int e = 0; e < E_; e++) {
        float s = gate_b[e];
        for (int c = 0; c < C_; c++) s += pooled[b * C_ + c] * gate_w[e * C_ + c];
        lg[e] = s;
    }
    float m = fmaxf(fmaxf(lg[0], lg[1]), fmaxf(lg[2], lg[3]));
    float ex[E_], sum = 0.f;
    for (int e = 0; e < E_; e++) { ex[e] = expf(lg[e] - m); sum += ex[e]; }
    for (int e = 0; e < E_; e++) ex[e] /= sum;
    // top-2, first-occurrence on ties (matches lax.top_k)
    int i1 = 0;
    for (int e = 1; e < E_; e++) if (ex[e] > ex[i1]) i1 = e;
    int i2 = -1;
    for (int e = 0; e < E_; e++) {
        if (e == i1) continue;
        if (i2 < 0 || ex[e] > ex[i2]) i2 = e;
    }
    for (int e = 0; e < E_; e++)
        ew[b * E_ + e] = (e == i1 || e == i2) ? ex[e] : 0.f;
}

// ---------------- weight transpose: [e][co][ci][3][3] -> [e][ci][tap][co] ----------------
__global__ __launch_bounds__(256) void wtr_kernel(const float* __restrict__ cw,
                                                  float* __restrict__ wT) {
    const int idx = blockIdx.x * 256 + threadIdx.x;  // over 4*64*9*64
    if (idx >= E_ * C_ * 9 * C_) return;
    const int co = idx & 63;
    const int t2 = idx >> 6;
    const int tap = t2 % 9;
    const int t3 = t2 / 9;
    const int ci = t3 & 63;
    const int e = t3 >> 6;
    wT[idx] = cw[(((e * C_ + co) * C_ + ci) * 9) + tap];
}

// ---------------- conv: one block per (b, h); lane=co, wave=16-px strip ----------------
__global__ __launch_bounds__(512) void conv_kernel(const float* __restrict__ in,
                                                   const float* __restrict__ kk,
                                                   const float* __restrict__ wT,
                                                   const float* __restrict__ cb,
                                                   const float* __restrict__ ew,
                                                   float* __restrict__ out) {
    const int bid = blockIdx.x;
    const int b = bid / H_;
    const int h = bid % H_;
    const int tid = threadIdx.x;
    const int lane = tid & 63;      // co
    const int wv = tid >> 6;        // 0..7
    const int x0 = wv * 16;

    __shared__ float sIn[CHUNK * 3 * W_];  // 48 KB

    // expert selection (uniform per block)
    float w0 = 0.f, w1 = 0.f;
    int e0 = 0, e1 = 0;
    {
        float we[E_];
#pragma unroll
        for (int e = 0; e < E_; e++) we[e] = ew[b * E_ + e];
        int found = 0;
        for (int e = 0; e < E_; e++) {
            if (we[e] != 0.f) {
                if (!found) { e0 = e; w0 = we[e]; found = 1; }
                else        { e1 = e; w1 = we[e]; }
            }
        }
        if (w1 == 0.f) e1 = e0;  // degenerate safety; w1=0 kills its term
    }

    float acc0[16], acc1[16];
#pragma unroll
    for (int i = 0; i < 16; i++) { acc0[i] = 0.f; acc1[i] = 0.f; }

    for (int cblk = 0; cblk < C_ / CHUNK; cblk++) {
        const int cbase = cblk * CHUNK;
        __syncthreads();
        // stage 3 rows x CHUNK ci x W into LDS (zero-pad missing rows)
        for (int f = tid; f < CHUNK * 3 * W_ / 4; f += 512) {
            const int fi = f * 4;
            const int ci = fi / (3 * W_);
            const int rem = fi - ci * 3 * W_;
            const int ky = rem / W_;
            const int x = rem - ky * W_;
            const int hh = h + ky - 1;
            float4 v = make_float4(0.f, 0.f, 0.f, 0.f);
            if (hh >= 0 && hh < H_) {
                v = *(const float4*)(in + ((size_t)(b * C_ + cbase + ci) * H_ + hh) * W_ + x);
            }
            *(float4*)(sIn + fi) = v;
        }
        __syncthreads();

        const float* wp0 = wT + (size_t)((e0 * C_ + cbase) * 9) * C_ + lane;
        const float* wp1 = wT + (size_t)((e1 * C_ + cbase) * 9) * C_ + lane;
        for (int ci = 0; ci < CHUNK; ci++) {
            float wa[9], wb[9];
#pragma unroll
            for (int t = 0; t < 9; t++) {
                wa[t] = wp0[(ci * 9 + t) * C_];
                wb[t] = wp1[(ci * 9 + t) * C_];
            }
            const float* rowp = sIn + ci * 3 * W_;
#pragma unroll
            for (int ky = 0; ky < 3; ky++) {
                float xin[18];
                const float* rp = rowp + ky * W_ + x0;
                xin[0] = (x0 == 0) ? 0.f : rp[-1];
#pragma unroll
                for (int j = 0; j < 16; j += 4) {
                    float4 v = *(const float4*)(rp + j);
                    xin[1 + j] = v.x; xin[2 + j] = v.y; xin[3 + j] = v.z; xin[4 + j] = v.w;
                }
                xin[17] = (x0 + 16 >= W_) ? 0.f : rp[16];
                const int t0 = ky * 3;
#pragma unroll
                for (int x = 0; x < 16; x++) {
                    acc0[x] += xin[x] * wa[t0] + xin[x + 1] * wa[t0 + 1] + xin[x + 2] * wa[t0 + 2];
                    acc1[x] += xin[x] * wb[t0] + xin[x + 1] * wb[t0 + 1] + xin[x + 2] * wb[t0 + 2];
                }
            }
        }
    }

    // epilogue: out = in + relu(acc0+b0)*k*w0 + relu(acc1+b1)*k*w1
    const float kv = kk[b * C_ + lane];
    const float b0v = cb[e0 * C_ + lane];
    const float b1v = cb[e1 * C_ + lane];
    const float kw0 = kv * w0, kw1 = kv * w1;
    const size_t obase = ((size_t)(b * C_ + lane) * H_ + h) * W_ + x0;
#pragma unroll
    for (int x = 0; x < 16; x += 4) {
        float4 iv = *(const float4*)(in + obase + x);
        float4 ov;
        ov.x = iv.x + fmaxf(acc0[x + 0] + b0v, 0.f) * kw0 + fmaxf(acc1[x + 0] + b1v, 0.f) * kw1;
        ov.y = iv.y + fmaxf(acc0[x + 1] + b0v, 0.f) * kw0 + fmaxf(acc1[x + 1] + b1v, 0.f) * kw1;
        ov.z = iv.z + fmaxf(acc0[x + 2] + b0v, 0.f) * kw0 + fmaxf(acc1[x + 2] + b1v, 0.f) * kw1;
        ov.w = iv.w + fmaxf(acc0[x + 3] + b0v, 0.f) * kw0 + fmaxf(acc1[x + 3] + b1v, 0.f) * kw1;
        *(float4*)(out + obase + x) = ov;
    }
}

extern "C" void kernel_launch(void* const* d_in, const int* in_sizes, int n_in,
                              void* d_out, int out_size, void* d_ws, size_t ws_size,
                              hipStream_t stream) {
    const float* inputs = (const float*)d_in[0];   // [16,64,128,128]
    const float* k      = (const float*)d_in[1];   // [16,64,1,1]
    const float* gate_w = (const float*)d_in[2];   // [4,64]
    const float* gate_b = (const float*)d_in[3];   // [4]
    const float* conv_w = (const float*)d_in[4];   // [4,64,64,3,3]
    const float* conv_b = (const float*)d_in[5];   // [4,64]
    float* out = (float*)d_out;

    float* ws = (float*)d_ws;
    float* wT     = ws + WT_OFF;
    float* pooled = ws + POOLED_OFF;
    float* ewbuf  = ws + EW_OFF;

    pool_kernel<<<B_ * C_, 256, 0, stream>>>(inputs, pooled);
    gate_kernel<<<1, 64, 0, stream>>>(pooled, gate_w, gate_b, ewbuf);
    wtr_kernel<<<(E_ * C_ * 9 * C_ + 255) / 256, 256, 0, stream>>>(conv_w, wT);
    conv_kernel<<<B_ * H_, 512, 0, stream>>>(inputs, k, wT, conv_b, ewbuf, out);
}

// Round 2
// 146.551 us; speedup vs baseline: 4.2743x; 4.2743x over previous
//
#include <hip/hip_runtime.h>

typedef __attribute__((ext_vector_type(8))) short bfrag8;    // 8 bf16 (4 VGPRs)
typedef __attribute__((ext_vector_type(16))) float f32x16;   // 32x32 MFMA acc
typedef __attribute__((ext_vector_type(4))) float f32x4;

#define B_ 16
#define C_ 64
#define H_ 128
#define W_ 128
#define E_ 4
#define HW_ (H_ * W_)

// ---- fast-path ws layout (bytes) ----
// inT: padded transposed input bf16 [16][130][130][64]
#define INT_ELEMS (16 * 130 * 130 * 64)
#define INT_BYTES (INT_ELEMS * 2)              // 34,611,200
#define WT_ELEMS (4 * 9 * 64 * 64)
#define WT_BYTES (WT_ELEMS * 2)                // 294,912
#define OFF_WT   INT_BYTES
#define OFF_POOL (INT_BYTES + WT_BYTES)        // 16*64 floats
#define OFF_EW   (OFF_POOL + 1024 * 4)         // 16*4 floats
#define WS_NEEDED ((size_t)(OFF_EW + 64 * 4))  // 34,910,464

// ---- fallback ws layout (floats): wTf[147456], pooled[1024], ew[64] ----
#define FB_WT_OFF 0
#define FB_POOLED_OFF 147456
#define FB_EW_OFF 148480

__device__ inline unsigned short f2bf(float f) {
    unsigned u = __builtin_bit_cast(unsigned, f);
    unsigned r = u + 0x7FFFu + ((u >> 16) & 1u);
    return (unsigned short)(r >> 16);
}

// ---------------- pool: mean over HW per (b,c) ----------------
__global__ __launch_bounds__(256) void pool_kernel(const float* __restrict__ in,
                                                   float* __restrict__ pooled) {
    const int bc = blockIdx.x;  // 0..1023
    const float* p = in + (size_t)bc * HW_;
    float s = 0.f;
    for (int i = threadIdx.x; i < HW_ / 4; i += 256) {
        float4 v = ((const float4*)p)[i];
        s += v.x + v.y + v.z + v.w;
    }
    for (int off = 32; off; off >>= 1) s += __shfl_down(s, off);
    __shared__ float red[4];
    const int lane = threadIdx.x & 63, wv = threadIdx.x >> 6;
    if (lane == 0) red[wv] = s;
    __syncthreads();
    if (threadIdx.x == 0)
        pooled[bc] = (red[0] + red[1] + red[2] + red[3]) * (1.0f / (float)HW_);
}

// ---------------- gate ----------------
__global__ void gate_kernel(const float* __restrict__ pooled,
                            const float* __restrict__ gate_w,
                            const float* __restrict__ gate_b,
                            float* __restrict__ ew) {
    const int b = threadIdx.x;
    if (b >= B_) return;
    float lg[E_];
    for (int e = 0; e < E_; e++) {
        float s = gate_b[e];
        for (int c = 0; c < C_; c++) s += pooled[b * C_ + c] * gate_w[e * C_ + c];
        lg[e] = s;
    }
    float m = fmaxf(fmaxf(lg[0], lg[1]), fmaxf(lg[2], lg[3]));
    float ex[E_], sum = 0.f;
    for (int e = 0; e < E_; e++) { ex[e] = expf(lg[e] - m); sum += ex[e]; }
    for (int e = 0; e < E_; e++) ex[e] /= sum;
    int i1 = 0;
    for (int e = 1; e < E_; e++) if (ex[e] > ex[i1]) i1 = e;
    int i2 = -1;
    for (int e = 0; e < E_; e++) {
        if (e == i1) continue;
        if (i2 < 0 || ex[e] > ex[i2]) i2 = e;
    }
    for (int e = 0; e < E_; e++)
        ew[b * E_ + e] = (e == i1 || e == i2) ? ex[e] : 0.f;
}

// ---------------- zero inT (pads stay 0) ----------------
__global__ __launch_bounds__(256) void zero_int(float4* __restrict__ p) {
    const int n = INT_BYTES / 16;
    for (int i = blockIdx.x * 256 + threadIdx.x; i < n; i += gridDim.x * 256)
        p[i] = make_float4(0.f, 0.f, 0.f, 0.f);
}

// ---------------- tcvt: NCHW fp32 -> padded [b][h+1][w+1][ci] bf16 ----------------
__global__ __launch_bounds__(256) void tcvt(const float* __restrict__ in,
                                            unsigned short* __restrict__ inT) {
    const int blk = blockIdx.x;           // b*128 + h
    const int b = blk >> 7, h = blk & 127;
    const int t = threadIdx.x;
    const int w = t >> 1, half = t & 1, ci0 = half * 32;
    bfrag8 vv[4];
#pragma unroll
    for (int i = 0; i < 32; i++)
        vv[i >> 3][i & 7] = (short)f2bf(in[((size_t)(b * C_ + ci0 + i) * H_ + h) * W_ + w]);
    unsigned short* dst = inT + (((size_t)b * 130 + h + 1) * 130 + (w + 1)) * 64 + ci0;
#pragma unroll
    for (int j = 0; j < 4; j++) *(bfrag8*)(dst + (j << 3)) = vv[j];
}

// ---------------- wcvt: conv_w fp32 [e][co][ci][3][3] -> wT bf16 [e][tap][co][ci] ----------------
__global__ __launch_bounds__(256) void wcvt(const float* __restrict__ cw,
                                            unsigned short* __restrict__ wT) {
    const int idx = blockIdx.x * 256 + threadIdx.x;
    if (idx >= WT_ELEMS) return;
    const int ci = idx & 63;
    int r = idx >> 6;
    const int co = r & 63; r >>= 6;
    const int tap = r % 9;
    const int e = r / 9;
    wT[idx] = f2bf(cw[(((e * C_ + co) * C_ + ci) * 9) + tap]);
}

// ---------------- conv via MFMA: block = (b,h) row, 4 waves ----------------
__global__ __launch_bounds__(256) void conv_mfma(const float* __restrict__ in,
                                                 const float* __restrict__ kk,
                                                 const float* __restrict__ cb,
                                                 const float* __restrict__ ew,
                                                 const unsigned short* __restrict__ inT,
                                                 const unsigned short* __restrict__ wT,
                                                 float* __restrict__ out) {
    const int blk = blockIdx.x;
    const int b = blk >> 7;
    const int h0 = blk & 127;            // output row
    const int tid = threadIdx.x;
    const int lane = tid & 63;
    const int wv = tid >> 6;             // 0..3
    const int ln = lane & 31;
    const int lh = lane >> 5;            // 0/1

    __shared__ unsigned short sIn[3 * 130 * 64];   // 49,920 B : [r][slot][ci] (ci-chunks XOR-swizzled)

    // expert selection (uniform per block)
    int e0 = 0, e1 = 0; float w0 = 0.f, w1 = 0.f;
    {
        int found = 0;
        for (int e = 0; e < E_; e++) {
            float we = ew[b * E_ + e];
            if (we != 0.f) {
                if (!found) { e0 = e; w0 = we; found = 1; }
                else        { e1 = e; w1 = we; }
            }
        }
        if (w1 == 0.f) e1 = e0;  // w1==0 kills the term
    }

    // ---- stage 3 padded rows via global_load_lds, pre-swizzled source ----
    // LDS chunk g (16B) = r*1040 + s*8 + c  holds inT[b][h0+r][s][ 8*(c^(s&7)) .. +7 ]
    for (int i = wv; i < 49; i += 4) {
        const int g = i * 64 + lane;
        if (g < 3120) {
            const int r = g / 1040;
            const int rem = g - r * 1040;
            const int s = rem >> 3;
            const int c = rem & 7;
            const unsigned short* src = inT +
                (((size_t)(b * 130 + h0 + r) * 130 + s) * 64 + ((c ^ (s & 7)) << 3));
            __builtin_amdgcn_global_load_lds(
                (const __attribute__((address_space(1))) void*)src,
                (__attribute__((address_space(3))) void*)(sIn + i * 512),
                16, 0, 0);
        }
    }
    __syncthreads();

    // ---- GEMM: wave tile 32co x 64px; A=weights (M=co), B=input (N=px) ----
    const int co0 = (wv >> 1) * 32;
    const int xh = (wv & 1) * 64;

    f32x16 accA0, accA1, accB0, accB1;
#pragma unroll
    for (int i = 0; i < 16; i++) { accA0[i] = 0.f; accA1[i] = 0.f; accB0[i] = 0.f; accB1[i] = 0.f; }

    const char* ldsb = (const char*)sIn;
    int ky = 0, kx = 0;
    for (int tap = 0; tap < 9; tap++) {
        const int s0 = xh + ln + kx;     // t=0 slot
        const int s1 = s0 + 32;          // t=1 slot
        const int rb = ky * 16640;       // row byte base
        const int sw0 = s0 & 7, sw1 = s1 & 7;
        const unsigned short* wa0 = wT + (((e0 * 9 + tap) * 64 + co0 + ln) << 6) + (lh << 3);
        const unsigned short* wa1 = wT + (((e1 * 9 + tap) * 64 + co0 + ln) << 6) + (lh << 3);
#pragma unroll
        for (int kb = 0; kb < 4; kb++) {
            const int ch = (kb << 1) | lh;
            bfrag8 a0 = *(const bfrag8*)(wa0 + (kb << 4));
            bfrag8 a1 = *(const bfrag8*)(wa1 + (kb << 4));
            bfrag8 b0 = *(const bfrag8*)(ldsb + rb + s0 * 128 + ((ch ^ sw0) << 4));
            bfrag8 b1 = *(const bfrag8*)(ldsb + rb + s1 * 128 + ((ch ^ sw1) << 4));
            accA0 = __builtin_amdgcn_mfma_f32_32x32x16_bf16(a0, b0, accA0, 0, 0, 0);
            accA1 = __builtin_amdgcn_mfma_f32_32x32x16_bf16(a0, b1, accA1, 0, 0, 0);
            accB0 = __builtin_amdgcn_mfma_f32_32x32x16_bf16(a1, b0, accB0, 0, 0, 0);
            accB1 = __builtin_amdgcn_mfma_f32_32x32x16_bf16(a1, b1, accB1, 0, 0, 0);
        }
        kx++;
        if (kx == 3) { kx = 0; ky++; }
    }

    // ---- epilogue: out = in + relu(acc+b)*k*w  (D: col=lane&31=px, row=co) ----
#pragma unroll
    for (int rg = 0; rg < 16; rg++) {
        const int co = co0 + (rg & 3) + 8 * (rg >> 2) + 4 * lh;
        const float kv = kk[b * C_ + co];
        const float f0 = kv * w0, f1 = kv * w1;
        const float bb0 = cb[e0 * C_ + co], bb1 = cb[e1 * C_ + co];
        const size_t rowbase = ((size_t)(b * C_ + co) * H_ + h0) * W_;
        {
            const int px = xh + ln;
            const float iv = in[rowbase + px];
            out[rowbase + px] = iv + fmaxf(accA0[rg] + bb0, 0.f) * f0
                                   + fmaxf(accB0[rg] + bb1, 0.f) * f1;
        }
        {
            const int px = xh + 32 + ln;
            const float iv = in[rowbase + px];
            out[rowbase + px] = iv + fmaxf(accA1[rg] + bb0, 0.f) * f0
                                   + fmaxf(accB1[rg] + bb1, 0.f) * f1;
        }
    }
}

// ================= fallback (round-1 fp32 path) =================
#define CHUNK 32

__global__ __launch_bounds__(256) void wtr_kernel(const float* __restrict__ cw,
                                                  float* __restrict__ wT) {
    const int idx = blockIdx.x * 256 + threadIdx.x;
    if (idx >= E_ * C_ * 9 * C_) return;
    const int co = idx & 63;
    const int t2 = idx >> 6;
    const int tap = t2 % 9;
    const int t3 = t2 / 9;
    const int ci = t3 & 63;
    const int e = t3 >> 6;
    wT[idx] = cw[(((e * C_ + co) * C_ + ci) * 9) + tap];
}

__global__ __launch_bounds__(512) void conv_fallback(const float* __restrict__ in,
                                                     const float* __restrict__ kk,
                                                     const float* __restrict__ wT,
                                                     const float* __restrict__ cb,
                                                     const float* __restrict__ ew,
                                                     float* __restrict__ out) {
    const int bid = blockIdx.x;
    const int b = bid / H_;
    const int h = bid % H_;
    const int tid = threadIdx.x;
    const int lane = tid & 63;
    const int wv = tid >> 6;
    const int x0 = wv * 16;

    __shared__ float sIn[CHUNK * 3 * W_];

    float w0 = 0.f, w1 = 0.f;
    int e0 = 0, e1 = 0;
    {
        float we[E_];
#pragma unroll
        for (int e = 0; e < E_; e++) we[e] = ew[b * E_ + e];
        int found = 0;
        for (int e = 0; e < E_; e++) {
            if (we[e] != 0.f) {
                if (!found) { e0 = e; w0 = we[e]; found = 1; }
                else        { e1 = e; w1 = we[e]; }
            }
        }
        if (w1 == 0.f) e1 = e0;
    }

    float acc0[16], acc1[16];
#pragma unroll
    for (int i = 0; i < 16; i++) { acc0[i] = 0.f; acc1[i] = 0.f; }

    for (int cblk = 0; cblk < C_ / CHUNK; cblk++) {
        const int cbase = cblk * CHUNK;
        __syncthreads();
        for (int f = tid; f < CHUNK * 3 * W_ / 4; f += 512) {
            const int fi = f * 4;
            const int ci = fi / (3 * W_);
            const int rem = fi - ci * 3 * W_;
            const int kyy = rem / W_;
            const int x = rem - kyy * W_;
            const int hh = h + kyy - 1;
            float4 v = make_float4(0.f, 0.f, 0.f, 0.f);
            if (hh >= 0 && hh < H_)
                v = *(const float4*)(in + ((size_t)(b * C_ + cbase + ci) * H_ + hh) * W_ + x);
            *(float4*)(sIn + fi) = v;
        }
        __syncthreads();

        const float* wp0 = wT + (size_t)((e0 * C_ + cbase) * 9) * C_ + lane;
        const float* wp1 = wT + (size_t)((e1 * C_ + cbase) * 9) * C_ + lane;
        for (int ci = 0; ci < CHUNK; ci++) {
            float wa[9], wb[9];
#pragma unroll
            for (int t = 0; t < 9; t++) {
                wa[t] = wp0[(ci * 9 + t) * C_];
                wb[t] = wp1[(ci * 9 + t) * C_];
            }
            const float* rowp = sIn + ci * 3 * W_;
#pragma unroll
            for (int kyy = 0; kyy < 3; kyy++) {
                float xin[18];
                const float* rp = rowp + kyy * W_ + x0;
                xin[0] = (x0 == 0) ? 0.f : rp[-1];
#pragma unroll
                for (int j = 0; j < 16; j += 4) {
                    float4 v = *(const float4*)(rp + j);
                    xin[1 + j] = v.x; xin[2 + j] = v.y; xin[3 + j] = v.z; xin[4 + j] = v.w;
                }
                xin[17] = (x0 + 16 >= W_) ? 0.f : rp[16];
                const int t0 = kyy * 3;
#pragma unroll
                for (int x = 0; x < 16; x++) {
                    acc0[x] += xin[x] * wa[t0] + xin[x + 1] * wa[t0 + 1] + xin[x + 2] * wa[t0 + 2];
                    acc1[x] += xin[x] * wb[t0] + xin[x + 1] * wb[t0 + 1] + xin[x + 2] * wb[t0 + 2];
                }
            }
        }
    }

    const float kv = kk[b * C_ + lane];
    const float b0v = cb[e0 * C_ + lane];
    const float b1v = cb[e1 * C_ + lane];
    const float kw0 = kv * w0, kw1 = kv * w1;
    const size_t obase = ((size_t)(b * C_ + lane) * H_ + h) * W_ + x0;
#pragma unroll
    for (int x = 0; x < 16; x += 4) {
        float4 iv = *(const float4*)(in + obase + x);
        float4 ov;
        ov.x = iv.x + fmaxf(acc0[x + 0] + b0v, 0.f) * kw0 + fmaxf(acc1[x + 0] + b1v, 0.f) * kw1;
        ov.y = iv.y + fmaxf(acc0[x + 1] + b0v, 0.f) * kw0 + fmaxf(acc1[x + 1] + b1v, 0.f) * kw1;
        ov.z = iv.z + fmaxf(acc0[x + 2] + b0v, 0.f) * kw0 + fmaxf(acc1[x + 2] + b1v, 0.f) * kw1;
        ov.w = iv.w + fmaxf(acc0[x + 3] + b0v, 0.f) * kw0 + fmaxf(acc1[x + 3] + b1v, 0.f) * kw1;
        *(float4*)(out + obase + x) = ov;
    }
}

extern "C" void kernel_launch(void* const* d_in, const int* in_sizes, int n_in,
                              void* d_out, int out_size, void* d_ws, size_t ws_size,
                              hipStream_t stream) {
    const float* inputs = (const float*)d_in[0];
    const float* k      = (const float*)d_in[1];
    const float* gate_w = (const float*)d_in[2];
    const float* gate_b = (const float*)d_in[3];
    const float* conv_w = (const float*)d_in[4];
    const float* conv_b = (const float*)d_in[5];
    float* out = (float*)d_out;
    char* wsb = (char*)d_ws;

    if (ws_size >= WS_NEEDED) {
        unsigned short* inT = (unsigned short*)(wsb);
        unsigned short* wT  = (unsigned short*)(wsb + OFF_WT);
        float* pooled = (float*)(wsb + OFF_POOL);
        float* ewbuf  = (float*)(wsb + OFF_EW);

        zero_int<<<2048, 256, 0, stream>>>((float4*)inT);
        tcvt<<<B_ * H_, 256, 0, stream>>>(inputs, inT);
        pool_kernel<<<B_ * C_, 256, 0, stream>>>(inputs, pooled);
        gate_kernel<<<1, 64, 0, stream>>>(pooled, gate_w, gate_b, ewbuf);
        wcvt<<<(WT_ELEMS + 255) / 256, 256, 0, stream>>>(conv_w, wT);
        conv_mfma<<<B_ * H_, 256, 0, stream>>>(inputs, k, conv_b, ewbuf, inT, wT, out);
    } else {
        float* ws = (float*)d_ws;
        float* wTf    = ws + FB_WT_OFF;
        float* pooled = ws + FB_POOLED_OFF;
        float* ewbuf  = ws + FB_EW_OFF;

        pool_kernel<<<B_ * C_, 256, 0, stream>>>(inputs, pooled);
        gate_kernel<<<1, 64, 0, stream>>>(pooled, gate_w, gate_b, ewbuf);
        wtr_kernel<<<(E_ * C_ * 9 * C_ + 255) / 256, 256, 0, stream>>>(conv_w, wTf);
        conv_fallback<<<B_ * H_, 512, 0, stream>>>(inputs, k, wTf, conv_b, ewbuf, out);
    }
}